// Round 1
// baseline (210.906 us; speedup 1.0000x reference)
//
#include <hip/hip_runtime.h>

#define BN 1024
#define NV 6890
#define NBETA 10
#define PB 207            // pose basis = 9*(J-1)
#define N3 20670          // NV*3
#define NCOL 20736        // 108*192 padded GEMM columns
#define NCHUNK 7          // K = 224 = 207 pose + 10 betas + 1 template + 6 zero
#define BT 32             // batches per k_vert block

typedef __bf16 bf16x8 __attribute__((ext_vector_type(8)));
typedef float  f32x4  __attribute__((ext_vector_type(4)));

__device__ __constant__ int c_par[24] = {-1,0,0,0,1,2,3,4,5,6,7,8,9,9,9,12,13,14,16,17,18,19,20,21};

__device__ inline unsigned short f2bf(float f) {
    unsigned u = __float_as_uint(f);
    u += 0x7fff + ((u >> 16) & 1);          // RNE
    return (unsigned short)(u >> 16);
}

__device__ inline void dma16(const void* g, void* l) {
    __builtin_amdgcn_global_load_lds(
        (const __attribute__((address_space(1))) unsigned int*)g,
        (__attribute__((address_space(3))) unsigned int*)l, 16, 0, 0);
}

// ---------------------------------------------------------------------------
// k_prep: one kernel, 4 disjoint block ranges.
//  A [0,567):      pd repack -> ws_pdt[kc][col][40] bf16 (pose;shape;template)
//  B [567,799):    pose_feature+betas+1 -> ws_pfb[b][232] bf16
//  C [799,1069):   lbs weights -> ws_wb[v][40] bf16 (v<6912)
//  D [1069,1645):  J_regressor partial reductions -> ws_jsp (8 seg x 72 x 11)
// ---------------------------------------------------------------------------
__global__ __launch_bounds__(256) void k_prep(const float* __restrict__ pd,
                                              const float* __restrict__ sd,
                                              const float* __restrict__ vtm,
                                              const float* __restrict__ Jr,
                                              const float* __restrict__ bpose,
                                              const float* __restrict__ betas,
                                              const float* __restrict__ w,
                                              unsigned short* __restrict__ ws_pdt,
                                              unsigned short* __restrict__ ws_pfb,
                                              unsigned short* __restrict__ ws_wb,
                                              float* __restrict__ ws_jsp)
{
    int blk = blockIdx.x;
    if (blk < 567) {
        int t = blk * 256 + threadIdx.x;           // 0..145151
        int kc = t / NCOL;
        int col = t - kc * NCOL;
        bool cok = col < N3;
        unsigned short vals[40];
        #pragma unroll
        for (int kk = 0; kk < 32; kk++) {
            int gk = kc * 32 + kk;
            float val = 0.f;
            if (cok) {
                if (gk < PB)             val = pd[(size_t)gk * N3 + col];
                else if (gk < PB + 10)   val = sd[(size_t)col * NBETA + (gk - PB)];
                else if (gk == PB + 10)  val = vtm[col];
            }
            vals[kk] = f2bf(val);
        }
        #pragma unroll
        for (int kk = 32; kk < 40; kk++) vals[kk] = 0;
        uint4* dst = (uint4*)(ws_pdt + (size_t)t * 40);
        #pragma unroll
        for (int q = 0; q < 5; q++) {
            uint4 u;
            u.x = vals[q*8+0] | ((unsigned)vals[q*8+1] << 16);
            u.y = vals[q*8+2] | ((unsigned)vals[q*8+3] << 16);
            u.z = vals[q*8+4] | ((unsigned)vals[q*8+5] << 16);
            u.w = vals[q*8+6] | ((unsigned)vals[q*8+7] << 16);
            dst[q] = u;
        }
    } else if (blk < 799) {
        int e0 = (blk - 567) * 1024 + threadIdx.x * 4;   // 232*1024 total
        unsigned short v4[4];
        #pragma unroll
        for (int r = 0; r < 4; r++) {
            int e = e0 + r;
            int b = e / 232, k = e - b * 232;
            float x = 0.f;
            if (k < PB) {
                x = bpose[(size_t)b * PB + k];
                int k9 = k % 9;
                if (k9 == 0 || k9 == 4 || k9 == 8) x -= 1.f;
            } else if (k < PB + 10) {
                x = betas[b * NBETA + (k - PB)];
            } else if (k == PB + 10) {
                x = 1.f;
            }
            v4[r] = f2bf(x);
        }
        uint2 u;
        u.x = v4[0] | ((unsigned)v4[1] << 16);
        u.y = v4[2] | ((unsigned)v4[3] << 16);
        *(uint2*)(ws_pfb + e0) = u;
    } else if (blk < 1069) {
        int e0 = (blk - 799) * 1024 + threadIdx.x * 4;   // 6912*40 total
        unsigned short v4[4];
        #pragma unroll
        for (int r = 0; r < 4; r++) {
            int e = e0 + r;
            int v = e / 40, j = e - v * 40;
            float val = (j < 24 && v < NV) ? w[(size_t)v * 24 + j] : 0.f;
            v4[r] = f2bf(val);
        }
        uint2 u;
        u.x = v4[0] | ((unsigned)v4[1] << 16);
        u.y = v4[2] | ((unsigned)v4[3] << 16);
        *(uint2*)(ws_wb + e0) = u;
    } else {
        int b2 = blk - 1069;           // 0..575
        int jc = b2 >> 3;              // 0..71
        int seg = b2 & 7;              // 0..7
        int j = jc / 3, c = jc % 3;
        int v0 = seg * 862;
        int v1 = v0 + 862; if (v1 > NV) v1 = NV;

        float acc[11];
        #pragma unroll
        for (int l = 0; l < 11; l++) acc[l] = 0.f;

        for (int v = v0 + threadIdx.x; v < v1; v += 256) {
            float r = Jr[j * NV + v];
            acc[10] += r * vtm[v * 3 + c];
            const float* s = sd + (size_t)(v * 3 + c) * NBETA;
            #pragma unroll
            for (int l = 0; l < NBETA; l++) acc[l] += r * s[l];
        }

        __shared__ float red[4][11];
        int lane = threadIdx.x & 63, wv = threadIdx.x >> 6;
        #pragma unroll
        for (int l = 0; l < 11; l++) {
            float x = acc[l];
            x += __shfl_down(x, 32, 64);
            x += __shfl_down(x, 16, 64);
            x += __shfl_down(x, 8, 64);
            x += __shfl_down(x, 4, 64);
            x += __shfl_down(x, 2, 64);
            x += __shfl_down(x, 1, 64);
            if (lane == 0) red[wv][l] = x;
        }
        __syncthreads();
        if (threadIdx.x == 0) {
            #pragma unroll
            for (int l = 0; l < 11; l++)
                ws_jsp[((size_t)seg * 72 + jc) * 11 + l]
                    = red[0][l] + red[1][l] + red[2][l] + red[3][l];
        }
    }
}

// ---------------------------------------------------------------------------
// k_chain: 64 blocks x 256 threads, 16 batches/block (16 lanes per batch).
// Sums js partials, joints + kinematic chain; emits bf16 ArT[b][12][40] + pj.
// ---------------------------------------------------------------------------
__global__ __launch_bounds__(256) void k_chain(const float* __restrict__ betas,
                                               const float* __restrict__ grot,
                                               const float* __restrict__ bpose,
                                               const float* __restrict__ ws_jsp,
                                               unsigned short* __restrict__ ws_artb,
                                               float* __restrict__ pj)
{
    __shared__ float js_s[72 * 11];
    __shared__ float jt[16][72];
    __shared__ float tl[16][288];
    __shared__ float am[16][288];
    int tid = threadIdx.x;

    for (int e = tid; e < 72 * 11; e += 256) {
        float s = 0.f;
        #pragma unroll
        for (int seg = 0; seg < 8; seg++)
            s += ws_jsp[(size_t)seg * 792 + e];
        js_s[e] = s;
    }
    __syncthreads();

    int lb = tid >> 4;              // 0..15
    int e  = tid & 15;              // 0..15
    int b  = blockIdx.x * 16 + lb;

    for (int idx = e; idx < 72; idx += 16) {
        float acc = js_s[idx * 11 + 10];
        const float* be = betas + b * NBETA;
        #pragma unroll
        for (int l = 0; l < NBETA; l++) acc += be[l] * js_s[idx * 11 + l];
        jt[lb][idx] = acc;
    }
    __syncthreads();

    for (int idx = e; idx < 288; idx += 16) {
        int j = idx / 12, e12 = idx % 12, m = e12 >> 2, n = e12 & 3;
        float val;
        if (n < 3) {
            val = (j == 0) ? grot[(size_t)b * 9 + m * 3 + n]
                           : bpose[((size_t)b * 23 + (j - 1)) * 9 + m * 3 + n];
        } else {
            val = jt[lb][j * 3 + m];
            if (j > 0) val -= jt[lb][c_par[j] * 3 + m];
        }
        tl[lb][idx] = val;
    }
    __syncthreads();

    if (e < 12) am[lb][e] = tl[lb][e];
    for (int i = 1; i < 24; i++) {
        __syncthreads();
        if (e < 12) {
            int p = c_par[i];
            int m = e >> 2, n = e & 3;
            float val = am[lb][p*12 + m*4 + 0] * tl[lb][i*12 + 0 + n]
                      + am[lb][p*12 + m*4 + 1] * tl[lb][i*12 + 4 + n]
                      + am[lb][p*12 + m*4 + 2] * tl[lb][i*12 + 8 + n];
            if (n == 3) val += am[lb][p*12 + m*4 + 3];
            am[lb][i*12 + e] = val;
        }
    }
    __syncthreads();

    for (int idx = e; idx < 72; idx += 16) {
        int j = idx / 3, m = idx % 3;
        pj[(size_t)b * 72 + idx] = am[lb][j*12 + m*4 + 3];
    }
    // ArT[b][col=m*4+n][j'] bf16, j' 0..39 (24..39 zero)
    for (int idx = e; idx < 480; idx += 16) {
        int col = idx / 40, j = idx - col * 40;
        float val = 0.f;
        if (j < 24) {
            int m = col >> 2, n = col & 3;
            if (n < 3) {
                val = am[lb][j*12 + col];
            } else {
                val = am[lb][j*12 + m*4 + 3]
                    - am[lb][j*12 + m*4 + 0] * jt[lb][j*3 + 0]
                    - am[lb][j*12 + m*4 + 1] * jt[lb][j*3 + 1]
                    - am[lb][j*12 + m*4 + 2] * jt[lb][j*3 + 2];
            }
        }
        ws_artb[(size_t)b * 480 + idx] = f2bf(val);
    }
}

// ---------------------------------------------------------------------------
// k_vert: phase 1 = MFMA GEMM (pf) x (pdT) -> v_posed; phase 2 = MFMA
// T = w @ ArT per 4-batch subtile, finished ENTIRELY in-register:
// each r16-quad of lanes holds one complete (vert,batch,m) row of T, so
// vh-multiply + 2x shfl_xor completes the dot product. No T_l LDS buffer,
// no per-sub barriers, no 4-way bank conflicts.
// LDS 40448 B -> 4 blocks/CU (was 52992 -> 3).
// ---------------------------------------------------------------------------
__global__ __launch_bounds__(256, 4) void k_vert(const unsigned short* __restrict__ ws_pdt,
                                                 const unsigned short* __restrict__ ws_pfb,
                                                 const unsigned short* __restrict__ ws_wb,
                                                 const unsigned short* __restrict__ ws_artb,
                                                 float* __restrict__ out)
{
    const int bb = blockIdx.x;            // 0..31
    const int vb = blockIdx.y;            // 0..107
    const int tid = threadIdx.x;
    const int wv = tid >> 6;
    const int lane = tid & 63;
    const int r16 = lane & 15;
    const int half8 = (lane >> 4) * 8;

    __shared__ __align__(16) unsigned char smem[40448];
    unsigned short* pdT_l = (unsigned short*)smem;            // [192][40] phase 1
    float*          disp_l = (float*)smem;                    // [32][196] phase 2
    unsigned short* ArT_l = (unsigned short*)(smem + 25088);  // [16*12][40]

    // ---- DMA ArT half 0 (batches bb*32 .. +16) and pdT chunk 0
    {
        const unsigned short* srcA = ws_artb + (size_t)(bb * BT) * 480;
        for (int i = wv; i < 15; i += 4)
            dma16((const char*)srcA + i * 1024 + lane * 16, (char*)ArT_l + i * 1024);
        const unsigned short* srcP = ws_pdt + (size_t)vb * 192 * 40;
        for (int i = wv; i < 15; i += 4)
            dma16((const char*)srcP + i * 1024 + lane * 16, (char*)pdT_l + i * 1024);
    }

    const unsigned short* pfbase = ws_pfb + (size_t)(bb * BT) * 232;
    // prologue a-frags (kc=0)
    bf16x8 a0 = *(const bf16x8*)(pfbase + r16 * 232 + half8);
    bf16x8 a1 = *(const bf16x8*)(pfbase + (16 + r16) * 232 + half8);

    __syncthreads();

    f32x4 acc[2][3];
    #pragma unroll
    for (int mt = 0; mt < 2; mt++)
        #pragma unroll
        for (int t = 0; t < 3; t++)
            acc[mt][t] = (f32x4){0.f, 0.f, 0.f, 0.f};

    #pragma unroll
    for (int kc = 0; kc < NCHUNK; kc++) {
        bf16x8 b0 = *(const bf16x8*)(pdT_l + (wv * 48 + r16) * 40 + half8);
        bf16x8 b1 = *(const bf16x8*)(pdT_l + (wv * 48 + 16 + r16) * 40 + half8);
        bf16x8 b2 = *(const bf16x8*)(pdT_l + (wv * 48 + 32 + r16) * 40 + half8);
        bf16x8 a0n, a1n;
        if (kc < NCHUNK - 1) {
            a0n = *(const bf16x8*)(pfbase + r16 * 232 + (kc + 1) * 32 + half8);
            a1n = *(const bf16x8*)(pfbase + (16 + r16) * 232 + (kc + 1) * 32 + half8);
        }
        __syncthreads();                      // all frag reads of chunk kc done
        if (kc < NCHUNK - 1) {
            const unsigned short* src = ws_pdt + ((size_t)(kc + 1) * NCOL + (size_t)vb * 192) * 40;
            for (int i = wv; i < 15; i += 4)
                dma16((const char*)src + i * 1024 + lane * 16, (char*)pdT_l + i * 1024);
        }
        acc[0][0] = __builtin_amdgcn_mfma_f32_16x16x32_bf16(a0, b0, acc[0][0], 0, 0, 0);
        acc[1][0] = __builtin_amdgcn_mfma_f32_16x16x32_bf16(a1, b0, acc[1][0], 0, 0, 0);
        acc[0][1] = __builtin_amdgcn_mfma_f32_16x16x32_bf16(a0, b1, acc[0][1], 0, 0, 0);
        acc[1][1] = __builtin_amdgcn_mfma_f32_16x16x32_bf16(a1, b1, acc[1][1], 0, 0, 0);
        acc[0][2] = __builtin_amdgcn_mfma_f32_16x16x32_bf16(a0, b2, acc[0][2], 0, 0, 0);
        acc[1][2] = __builtin_amdgcn_mfma_f32_16x16x32_bf16(a1, b2, acc[1][2], 0, 0, 0);
        a0 = a0n; a1 = a1n;
        if (kc < NCHUNK - 1) __syncthreads(); // DMA(kc+1) landed
    }

    // ---- scatter v_posed into disp_l (overlays pdT; all reads done at last sync)
    // stride 196: lane-groups land at bank offsets {0,16,0,16} -> 2-way (free)
    #pragma unroll
    for (int mt = 0; mt < 2; mt++) {
        #pragma unroll
        for (int t = 0; t < 3; t++) {
            int col = wv * 48 + t * 16 + r16;
            int brow = mt * 16 + (lane >> 4) * 4;
            #pragma unroll
            for (int r = 0; r < 4; r++)
                disp_l[(brow + r) * 196 + col] = acc[mt][t][r];
        }
    }
    __syncthreads();

    // ---- phase 2 (barrier-free sub loop, in-register epilogue)
    bf16x8 aw = *(const bf16x8*)(ws_wb + (size_t)(vb * 64 + wv * 16 + r16) * 40 + half8);

    // This wave's verts: wv*16 + (lane>>4)*4 + r   (MFMA C-row = (lane>>4)*4+r)
    const int vbase = wv * 16 + (half8 >> 1);      // (lane>>4)*4
    const int n = r16 & 3;                         // artcol & 3; n==3 -> translation col
    // Per-t decode of artcol = t*16 + r16: q=artcol>>2, b_local=q/3, m=q%3.
    int bl[3], mm[3];
    #pragma unroll
    for (int t = 0; t < 3; t++) {
        int q = 4 * t + (r16 >> 2);                // 0..11
        bl[t] = (q * 11) >> 5;                     // q/3 for q in [0,12)
        mm[t] = q - 3 * bl[t];
    }

    for (int half = 0; half < 2; half++) {
        if (half == 1) {
            __syncthreads();                       // all half-0 ArT reads done
            const unsigned short* srcA = ws_artb + (size_t)(bb * BT + 16) * 480;
            for (int i = wv; i < 15; i += 4)
                dma16((const char*)srcA + i * 1024 + lane * 16, (char*)ArT_l + i * 1024);
            __syncthreads();                       // DMA landed
        }
        for (int s = 0; s < 4; s++) {
            int sub = half * 4 + s;
            bf16x8 bA0 = *(const bf16x8*)(ArT_l + (s * 48 + r16) * 40 + half8);
            bf16x8 bA1 = *(const bf16x8*)(ArT_l + (s * 48 + 16 + r16) * 40 + half8);
            bf16x8 bA2 = *(const bf16x8*)(ArT_l + (s * 48 + 32 + r16) * 40 + half8);
            f32x4 z = (f32x4){0.f, 0.f, 0.f, 0.f};
            f32x4 t0 = __builtin_amdgcn_mfma_f32_16x16x32_bf16(aw, bA0, z, 0, 0, 0);
            f32x4 t1 = __builtin_amdgcn_mfma_f32_16x16x32_bf16(aw, bA1, z, 0, 0, 0);
            f32x4 t2 = __builtin_amdgcn_mfma_f32_16x16x32_bf16(aw, bA2, z, 0, 0, 0);

            // Each r16-quad holds T[vert][b_local][m][0..3]; finish the dot
            // in-register: vh multiply + butterfly over lanes ^1, ^2.
            #pragma unroll
            for (int t = 0; t < 3; t++) {
                f32x4 tt = (t == 0) ? t0 : (t == 1) ? t1 : t2;
                const float* drow = disp_l + (sub * 4 + bl[t]) * 196 + vbase * 3 + n;
                size_t obase = (size_t)(bb * BT + sub * 4 + bl[t]) * N3
                             + (size_t)(vb * 64 + vbase) * 3 + mm[t];
                int vg0 = vb * 64 + vbase;
                #pragma unroll
                for (int r = 0; r < 4; r++) {
                    float vh = (n < 3) ? drow[r * 3] : 1.0f;
                    float p = tt[r] * vh;
                    p += __shfl_xor(p, 1);
                    p += __shfl_xor(p, 2);
                    if (n == 0 && (vg0 + r) < NV)
                        out[obase + (size_t)r * 3] = p;
                }
            }
        }
    }
}

// ---------------------------------------------------------------------------
extern "C" void kernel_launch(void* const* d_in, const int* in_sizes, int n_in,
                              void* d_out, int out_size, void* d_ws, size_t ws_size,
                              hipStream_t stream) {
    const float* betas = (const float*)d_in[0];
    const float* grot  = (const float*)d_in[1];
    const float* bpose = (const float*)d_in[2];
    const float* vtm   = (const float*)d_in[3];
    const float* sd    = (const float*)d_in[4];
    const float* pd    = (const float*)d_in[5];
    const float* Jr    = (const float*)d_in[6];
    const float* w     = (const float*)d_in[7];
    float* out = (float*)d_out;

    char* ws = (char*)d_ws;
    unsigned short* ws_pdt  = (unsigned short*)(ws);              // 11,612,160 B
    unsigned short* ws_pfb  = (unsigned short*)(ws + 11612160);   //    475,136 B
    unsigned short* ws_wb   = (unsigned short*)(ws + 12087296);   //    552,960 B
    float*          ws_jsp  = (float*)         (ws + 12640256);   //     25,344 B
    unsigned short* ws_artb = (unsigned short*)(ws + 12665600);   //    983,040 B

    k_prep<<<1645, 256, 0, stream>>>(pd, sd, vtm, Jr, bpose, betas, w,
                                     ws_pdt, ws_pfb, ws_wb, ws_jsp);
    k_chain<<<BN / 16, 256, 0, stream>>>(betas, grot, bpose, ws_jsp, ws_artb,
                                         out + (size_t)BN * N3);
    k_vert<<<dim3(32, 108), 256, 0, stream>>>(ws_pdt, ws_pfb, ws_wb, ws_artb, out);
}

// Round 2
// 180.175 us; speedup vs baseline: 1.1706x; 1.1706x over previous
//
#include <hip/hip_runtime.h>

#define BN 1024
#define NV 6890
#define NBETA 10
#define PB 207            // pose basis = 9*(J-1)
#define N3 20670          // NV*3
#define NCOL 20736        // 108*192 padded GEMM columns
#define NCHUNK 7          // K = 224 = 207 pose + 10 betas + 1 template + 6 zero
#define BT 32             // batches per k_vert block

typedef __bf16 bf16x8 __attribute__((ext_vector_type(8)));
typedef float  f32x4  __attribute__((ext_vector_type(4)));

__device__ __constant__ int c_par[24] = {-1,0,0,0,1,2,3,4,5,6,7,8,9,9,9,12,13,14,16,17,18,19,20,21};

__device__ inline unsigned short f2bf(float f) {
    unsigned u = __float_as_uint(f);
    u += 0x7fff + ((u >> 16) & 1);          // RNE
    return (unsigned short)(u >> 16);
}

__device__ inline void dma16(const void* g, void* l) {
    __builtin_amdgcn_global_load_lds(
        (const __attribute__((address_space(1))) unsigned int*)g,
        (__attribute__((address_space(3))) unsigned int*)l, 16, 0, 0);
}

// ---------------------------------------------------------------------------
// k_prep: one kernel, 4 disjoint block ranges.
//  A [0,567):      pd repack -> ws_pdt[kc][col][40] bf16 (pose;shape;template)
//  B [567,799):    pose_feature+betas+1 -> ws_pfb[b][232] bf16
//  C [799,1069):   lbs weights -> ws_wb[v][40] bf16 (v<6912)
//  D [1069,1645):  J_regressor partial reductions -> ws_jsp (8 seg x 72 x 11)
// ---------------------------------------------------------------------------
__global__ __launch_bounds__(256) void k_prep(const float* __restrict__ pd,
                                              const float* __restrict__ sd,
                                              const float* __restrict__ vtm,
                                              const float* __restrict__ Jr,
                                              const float* __restrict__ bpose,
                                              const float* __restrict__ betas,
                                              const float* __restrict__ w,
                                              unsigned short* __restrict__ ws_pdt,
                                              unsigned short* __restrict__ ws_pfb,
                                              unsigned short* __restrict__ ws_wb,
                                              float* __restrict__ ws_jsp)
{
    int blk = blockIdx.x;
    if (blk < 567) {
        int t = blk * 256 + threadIdx.x;           // 0..145151
        int kc = t / NCOL;
        int col = t - kc * NCOL;
        bool cok = col < N3;
        unsigned short vals[40];
        #pragma unroll
        for (int kk = 0; kk < 32; kk++) {
            int gk = kc * 32 + kk;
            float val = 0.f;
            if (cok) {
                if (gk < PB)             val = pd[(size_t)gk * N3 + col];
                else if (gk < PB + 10)   val = sd[(size_t)col * NBETA + (gk - PB)];
                else if (gk == PB + 10)  val = vtm[col];
            }
            vals[kk] = f2bf(val);
        }
        #pragma unroll
        for (int kk = 32; kk < 40; kk++) vals[kk] = 0;
        uint4* dst = (uint4*)(ws_pdt + (size_t)t * 40);
        #pragma unroll
        for (int q = 0; q < 5; q++) {
            uint4 u;
            u.x = vals[q*8+0] | ((unsigned)vals[q*8+1] << 16);
            u.y = vals[q*8+2] | ((unsigned)vals[q*8+3] << 16);
            u.z = vals[q*8+4] | ((unsigned)vals[q*8+5] << 16);
            u.w = vals[q*8+6] | ((unsigned)vals[q*8+7] << 16);
            dst[q] = u;
        }
    } else if (blk < 799) {
        int e0 = (blk - 567) * 1024 + threadIdx.x * 4;   // 232*1024 total
        unsigned short v4[4];
        #pragma unroll
        for (int r = 0; r < 4; r++) {
            int e = e0 + r;
            int b = e / 232, k = e - b * 232;
            float x = 0.f;
            if (k < PB) {
                x = bpose[(size_t)b * PB + k];
                int k9 = k % 9;
                if (k9 == 0 || k9 == 4 || k9 == 8) x -= 1.f;
            } else if (k < PB + 10) {
                x = betas[b * NBETA + (k - PB)];
            } else if (k == PB + 10) {
                x = 1.f;
            }
            v4[r] = f2bf(x);
        }
        uint2 u;
        u.x = v4[0] | ((unsigned)v4[1] << 16);
        u.y = v4[2] | ((unsigned)v4[3] << 16);
        *(uint2*)(ws_pfb + e0) = u;
    } else if (blk < 1069) {
        int e0 = (blk - 799) * 1024 + threadIdx.x * 4;   // 6912*40 total
        unsigned short v4[4];
        #pragma unroll
        for (int r = 0; r < 4; r++) {
            int e = e0 + r;
            int v = e / 40, j = e - v * 40;
            float val = (j < 24 && v < NV) ? w[(size_t)v * 24 + j] : 0.f;
            v4[r] = f2bf(val);
        }
        uint2 u;
        u.x = v4[0] | ((unsigned)v4[1] << 16);
        u.y = v4[2] | ((unsigned)v4[3] << 16);
        *(uint2*)(ws_wb + e0) = u;
    } else {
        int b2 = blk - 1069;           // 0..575
        int jc = b2 >> 3;              // 0..71
        int seg = b2 & 7;              // 0..7
        int j = jc / 3, c = jc % 3;
        int v0 = seg * 862;
        int v1 = v0 + 862; if (v1 > NV) v1 = NV;

        float acc[11];
        #pragma unroll
        for (int l = 0; l < 11; l++) acc[l] = 0.f;

        for (int v = v0 + threadIdx.x; v < v1; v += 256) {
            float r = Jr[j * NV + v];
            acc[10] += r * vtm[v * 3 + c];
            const float* s = sd + (size_t)(v * 3 + c) * NBETA;
            #pragma unroll
            for (int l = 0; l < NBETA; l++) acc[l] += r * s[l];
        }

        __shared__ float red[4][11];
        int lane = threadIdx.x & 63, wv = threadIdx.x >> 6;
        #pragma unroll
        for (int l = 0; l < 11; l++) {
            float x = acc[l];
            x += __shfl_down(x, 32, 64);
            x += __shfl_down(x, 16, 64);
            x += __shfl_down(x, 8, 64);
            x += __shfl_down(x, 4, 64);
            x += __shfl_down(x, 2, 64);
            x += __shfl_down(x, 1, 64);
            if (lane == 0) red[wv][l] = x;
        }
        __syncthreads();
        if (threadIdx.x == 0) {
            #pragma unroll
            for (int l = 0; l < 11; l++)
                ws_jsp[((size_t)seg * 72 + jc) * 11 + l]
                    = red[0][l] + red[1][l] + red[2][l] + red[3][l];
        }
    }
}

// ---------------------------------------------------------------------------
// k_chain: 64 blocks x 256 threads, 16 batches/block (16 lanes per batch).
// Sums js partials, joints + kinematic chain; emits bf16 ArT[b][12][40] + pj.
// ---------------------------------------------------------------------------
__global__ __launch_bounds__(256) void k_chain(const float* __restrict__ betas,
                                               const float* __restrict__ grot,
                                               const float* __restrict__ bpose,
                                               const float* __restrict__ ws_jsp,
                                               unsigned short* __restrict__ ws_artb,
                                               float* __restrict__ pj)
{
    __shared__ float js_s[72 * 11];
    __shared__ float jt[16][72];
    __shared__ float tl[16][288];
    __shared__ float am[16][288];
    int tid = threadIdx.x;

    for (int e = tid; e < 72 * 11; e += 256) {
        float s = 0.f;
        #pragma unroll
        for (int seg = 0; seg < 8; seg++)
            s += ws_jsp[(size_t)seg * 792 + e];
        js_s[e] = s;
    }
    __syncthreads();

    int lb = tid >> 4;              // 0..15
    int e  = tid & 15;              // 0..15
    int b  = blockIdx.x * 16 + lb;

    for (int idx = e; idx < 72; idx += 16) {
        float acc = js_s[idx * 11 + 10];
        const float* be = betas + b * NBETA;
        #pragma unroll
        for (int l = 0; l < NBETA; l++) acc += be[l] * js_s[idx * 11 + l];
        jt[lb][idx] = acc;
    }
    __syncthreads();

    for (int idx = e; idx < 288; idx += 16) {
        int j = idx / 12, e12 = idx % 12, m = e12 >> 2, n = e12 & 3;
        float val;
        if (n < 3) {
            val = (j == 0) ? grot[(size_t)b * 9 + m * 3 + n]
                           : bpose[((size_t)b * 23 + (j - 1)) * 9 + m * 3 + n];
        } else {
            val = jt[lb][j * 3 + m];
            if (j > 0) val -= jt[lb][c_par[j] * 3 + m];
        }
        tl[lb][idx] = val;
    }
    __syncthreads();

    if (e < 12) am[lb][e] = tl[lb][e];
    for (int i = 1; i < 24; i++) {
        __syncthreads();
        if (e < 12) {
            int p = c_par[i];
            int m = e >> 2, n = e & 3;
            float val = am[lb][p*12 + m*4 + 0] * tl[lb][i*12 + 0 + n]
                      + am[lb][p*12 + m*4 + 1] * tl[lb][i*12 + 4 + n]
                      + am[lb][p*12 + m*4 + 2] * tl[lb][i*12 + 8 + n];
            if (n == 3) val += am[lb][p*12 + m*4 + 3];
            am[lb][i*12 + e] = val;
        }
    }
    __syncthreads();

    for (int idx = e; idx < 72; idx += 16) {
        int j = idx / 3, m = idx % 3;
        pj[(size_t)b * 72 + idx] = am[lb][j*12 + m*4 + 3];
    }
    // ArT[b][col=m*4+n][j'] bf16, j' 0..39 (24..39 zero)
    for (int idx = e; idx < 480; idx += 16) {
        int col = idx / 40, j = idx - col * 40;
        float val = 0.f;
        if (j < 24) {
            int m = col >> 2, n = col & 3;
            if (n < 3) {
                val = am[lb][j*12 + col];
            } else {
                val = am[lb][j*12 + m*4 + 3]
                    - am[lb][j*12 + m*4 + 0] * jt[lb][j*3 + 0]
                    - am[lb][j*12 + m*4 + 1] * jt[lb][j*3 + 1]
                    - am[lb][j*12 + m*4 + 2] * jt[lb][j*3 + 2];
            }
        }
        ws_artb[(size_t)b * 480 + idx] = f2bf(val);
    }
}

// ---------------------------------------------------------------------------
// k_vert: phase 1 = MFMA GEMM (pf) x (pdT) -> v_posed; phase 2 = MFMA with
// SWAPPED operands: C[artcol][vert] = mfma(ArT_frag, w_frag). Lane (g=lane>>4)
// then holds, per tile t, all 4 n-components of (batch,m) with q=4t+g in its
// 4 accumulator regs -> epilogue is 4 in-lane FMAs + 1 store. No T_l buffer,
// no shuffles, no per-sub barriers, full store-lane utilization.
// LDS 40448 B -> 4 blocks/CU.
// ---------------------------------------------------------------------------
__global__ __launch_bounds__(256, 4) void k_vert(const unsigned short* __restrict__ ws_pdt,
                                                 const unsigned short* __restrict__ ws_pfb,
                                                 const unsigned short* __restrict__ ws_wb,
                                                 const unsigned short* __restrict__ ws_artb,
                                                 float* __restrict__ out)
{
    const int bb = blockIdx.x;            // 0..31
    const int vb = blockIdx.y;            // 0..107
    const int tid = threadIdx.x;
    const int wv = tid >> 6;
    const int lane = tid & 63;
    const int r16 = lane & 15;
    const int half8 = (lane >> 4) * 8;

    __shared__ __align__(16) unsigned char smem[40448];
    unsigned short* pdT_l = (unsigned short*)smem;            // [192][40] phase 1
    float*          disp_l = (float*)smem;                    // [32][196] phase 2
    unsigned short* ArT_l = (unsigned short*)(smem + 25088);  // [16*12][40]

    // ---- DMA ArT half 0 (batches bb*32 .. +16) and pdT chunk 0
    {
        const unsigned short* srcA = ws_artb + (size_t)(bb * BT) * 480;
        for (int i = wv; i < 15; i += 4)
            dma16((const char*)srcA + i * 1024 + lane * 16, (char*)ArT_l + i * 1024);
        const unsigned short* srcP = ws_pdt + (size_t)vb * 192 * 40;
        for (int i = wv; i < 15; i += 4)
            dma16((const char*)srcP + i * 1024 + lane * 16, (char*)pdT_l + i * 1024);
    }

    const unsigned short* pfbase = ws_pfb + (size_t)(bb * BT) * 232;
    // prologue a-frags (kc=0)
    bf16x8 a0 = *(const bf16x8*)(pfbase + r16 * 232 + half8);
    bf16x8 a1 = *(const bf16x8*)(pfbase + (16 + r16) * 232 + half8);

    __syncthreads();

    f32x4 acc[2][3];
    #pragma unroll
    for (int mt = 0; mt < 2; mt++)
        #pragma unroll
        for (int t = 0; t < 3; t++)
            acc[mt][t] = (f32x4){0.f, 0.f, 0.f, 0.f};

    #pragma unroll
    for (int kc = 0; kc < NCHUNK; kc++) {
        bf16x8 b0 = *(const bf16x8*)(pdT_l + (wv * 48 + r16) * 40 + half8);
        bf16x8 b1 = *(const bf16x8*)(pdT_l + (wv * 48 + 16 + r16) * 40 + half8);
        bf16x8 b2 = *(const bf16x8*)(pdT_l + (wv * 48 + 32 + r16) * 40 + half8);
        bf16x8 a0n, a1n;
        if (kc < NCHUNK - 1) {
            a0n = *(const bf16x8*)(pfbase + r16 * 232 + (kc + 1) * 32 + half8);
            a1n = *(const bf16x8*)(pfbase + (16 + r16) * 232 + (kc + 1) * 32 + half8);
        }
        __syncthreads();                      // all frag reads of chunk kc done
        if (kc < NCHUNK - 1) {
            const unsigned short* src = ws_pdt + ((size_t)(kc + 1) * NCOL + (size_t)vb * 192) * 40;
            for (int i = wv; i < 15; i += 4)
                dma16((const char*)src + i * 1024 + lane * 16, (char*)pdT_l + i * 1024);
        }
        acc[0][0] = __builtin_amdgcn_mfma_f32_16x16x32_bf16(a0, b0, acc[0][0], 0, 0, 0);
        acc[1][0] = __builtin_amdgcn_mfma_f32_16x16x32_bf16(a1, b0, acc[1][0], 0, 0, 0);
        acc[0][1] = __builtin_amdgcn_mfma_f32_16x16x32_bf16(a0, b1, acc[0][1], 0, 0, 0);
        acc[1][1] = __builtin_amdgcn_mfma_f32_16x16x32_bf16(a1, b1, acc[1][1], 0, 0, 0);
        acc[0][2] = __builtin_amdgcn_mfma_f32_16x16x32_bf16(a0, b2, acc[0][2], 0, 0, 0);
        acc[1][2] = __builtin_amdgcn_mfma_f32_16x16x32_bf16(a1, b2, acc[1][2], 0, 0, 0);
        a0 = a0n; a1 = a1n;
        if (kc < NCHUNK - 1) __syncthreads(); // DMA(kc+1) landed
    }

    // ---- scatter v_posed into disp_l (overlays pdT; all reads done at last sync)
    // stride 196: lane-groups land at bank offsets {0,16,0,16} -> 2-way (free)
    #pragma unroll
    for (int mt = 0; mt < 2; mt++) {
        #pragma unroll
        for (int t = 0; t < 3; t++) {
            int col = wv * 48 + t * 16 + r16;
            int brow = mt * 16 + (lane >> 4) * 4;
            #pragma unroll
            for (int r = 0; r < 4; r++)
                disp_l[(brow + r) * 196 + col] = acc[mt][t][r];
        }
    }
    __syncthreads();

    // ---- phase 2 (barrier-free sub loop, transposed-MFMA epilogue)
    // w fragment used as the B operand: B[j][vert], vert = lane&15.
    bf16x8 aw = *(const bf16x8*)(ws_wb + (size_t)(vb * 64 + wv * 16 + r16) * 40 + half8);

    const int g = lane >> 4;
    const int v16 = wv * 16 + r16;            // vert within block (C col)
    const int vg = vb * 64 + v16;             // global vert
    // Per tile t: artcol = 16t + 4g + r -> q = 4t+g (lane-const), n = r (reg).
    int bl[3], mm[3];
    #pragma unroll
    for (int t = 0; t < 3; t++) {
        int q = 4 * t + g;                    // 0..11
        bl[t] = (q * 11) >> 5;                // q/3 for q in [0,12)
        mm[t] = q - 3 * bl[t];
    }

    for (int half = 0; half < 2; half++) {
        if (half == 1) {
            __syncthreads();                  // all half-0 ArT reads done
            const unsigned short* srcA = ws_artb + (size_t)(bb * BT + 16) * 480;
            for (int i = wv; i < 15; i += 4)
                dma16((const char*)srcA + i * 1024 + lane * 16, (char*)ArT_l + i * 1024);
            __syncthreads();                  // DMA landed
        }
        for (int s = 0; s < 4; s++) {
            int sub = half * 4 + s;
            bf16x8 bA0 = *(const bf16x8*)(ArT_l + (s * 48 + r16) * 40 + half8);
            bf16x8 bA1 = *(const bf16x8*)(ArT_l + (s * 48 + 16 + r16) * 40 + half8);
            bf16x8 bA2 = *(const bf16x8*)(ArT_l + (s * 48 + 32 + r16) * 40 + half8);
            f32x4 z = (f32x4){0.f, 0.f, 0.f, 0.f};
            // swapped operands: C[artcol][vert]
            f32x4 t0 = __builtin_amdgcn_mfma_f32_16x16x32_bf16(bA0, aw, z, 0, 0, 0);
            f32x4 t1 = __builtin_amdgcn_mfma_f32_16x16x32_bf16(bA1, aw, z, 0, 0, 0);
            f32x4 t2 = __builtin_amdgcn_mfma_f32_16x16x32_bf16(bA2, aw, z, 0, 0, 0);

            #pragma unroll
            for (int t = 0; t < 3; t++) {
                f32x4 tt = (t == 0) ? t0 : (t == 1) ? t1 : t2;
                int row = sub * 4 + bl[t];
                const float* d = disp_l + row * 196 + v16 * 3;
                float x = d[0], y = d[1], zz = d[2];
                float p = tt[0] * x + tt[1] * y + tt[2] * zz + tt[3];
                if (vg < NV)
                    out[(size_t)(bb * BT + row) * N3 + (size_t)vg * 3 + mm[t]] = p;
            }
        }
    }
}

// ---------------------------------------------------------------------------
extern "C" void kernel_launch(void* const* d_in, const int* in_sizes, int n_in,
                              void* d_out, int out_size, void* d_ws, size_t ws_size,
                              hipStream_t stream) {
    const float* betas = (const float*)d_in[0];
    const float* grot  = (const float*)d_in[1];
    const float* bpose = (const float*)d_in[2];
    const float* vtm   = (const float*)d_in[3];
    const float* sd    = (const float*)d_in[4];
    const float* pd    = (const float*)d_in[5];
    const float* Jr    = (const float*)d_in[6];
    const float* w     = (const float*)d_in[7];
    float* out = (float*)d_out;

    char* ws = (char*)d_ws;
    unsigned short* ws_pdt  = (unsigned short*)(ws);              // 11,612,160 B
    unsigned short* ws_pfb  = (unsigned short*)(ws + 11612160);   //    475,136 B
    unsigned short* ws_wb   = (unsigned short*)(ws + 12087296);   //    552,960 B
    float*          ws_jsp  = (float*)         (ws + 12640256);   //     25,344 B
    unsigned short* ws_artb = (unsigned short*)(ws + 12665600);   //    983,040 B

    k_prep<<<1645, 256, 0, stream>>>(pd, sd, vtm, Jr, bpose, betas, w,
                                     ws_pdt, ws_pfb, ws_wb, ws_jsp);
    k_chain<<<BN / 16, 256, 0, stream>>>(betas, grot, bpose, ws_jsp, ws_artb,
                                         out + (size_t)BN * N3);
    k_vert<<<dim3(32, 108), 256, 0, stream>>>(ws_pdt, ws_pfb, ws_wb, ws_artb, out);
}